// Round 1
// baseline (1323.306 us; speedup 1.0000x reference)
//
#include <hip/hip_runtime.h>
#include <hip/hip_bf16.h>

#define TT 2048
#define BT 4096
#define DD 512
#define SS 256
#define VV 32000
#define LL 4
#define DFF_ 1368
#define DFFP 1408

typedef __attribute__((ext_vector_type(8))) short s16x8;
typedef __attribute__((ext_vector_type(4))) float f32x4;

static __device__ __forceinline__ unsigned short f2bf(float x) {
  __hip_bfloat16 t = __float2bfloat16(x);
  return __builtin_bit_cast(unsigned short, t);
}
static __device__ __forceinline__ float bf2f(unsigned short u) {
  __hip_bfloat16 t = __builtin_bit_cast(__hip_bfloat16, u);
  return __bfloat162float(t);
}

// ---------------- cast kernels ----------------
__global__ void cast_kernel(const float* __restrict__ s, unsigned short* __restrict__ d, long n) {
  long i = (long)blockIdx.x * 256 + threadIdx.x;
  if (i < n) d[i] = f2bf(s[i]);
}

// src [LL][R0][C] -> dst [LL][R1][C], rows >= R0 zero
__global__ void cast_pad_rows_kernel(const float* __restrict__ s, unsigned short* __restrict__ d,
                                     int R0, int R1, int C) {
  long i = (long)blockIdx.x * 256 + threadIdx.x;
  long n = (long)LL * R1 * C;
  if (i >= n) return;
  int c = (int)(i % C);
  long t2 = i / C;
  int r = (int)(t2 % R1);
  int l = (int)(t2 / R1);
  float v = (r < R0) ? s[((long)l * R0 + r) * C + c] : 0.f;
  d[i] = f2bf(v);
}

// src [LL][R][C0] -> dst [LL][R][C1], cols >= C0 zero
__global__ void cast_pad_cols_kernel(const float* __restrict__ s, unsigned short* __restrict__ d,
                                     int R, int C0, int C1) {
  long i = (long)blockIdx.x * 256 + threadIdx.x;
  long n = (long)LL * R * C1;
  if (i >= n) return;
  int c = (int)(i % C1);
  long t2 = i / C1;
  int r = (int)(t2 % R);
  int l = (int)(t2 / R);
  float v = (c < C0) ? s[((long)l * R + r) * C0 + c] : 0.f;
  d[i] = f2bf(v);
}

// ---------------- embedding ----------------
__global__ void embed_kernel(const int* __restrict__ x, const float* __restrict__ emb,
                             const float* __restrict__ pos, float* __restrict__ h) {
  int row = blockIdx.x;           // 0..4095 = b*T + t
  int t = row & (TT - 1);
  int tok = x[row];
  const float4* e = (const float4*)(emb + (long)tok * DD);
  const float4* p = (const float4*)(pos + (long)t * DD);
  float4* o = (float4*)(h + (long)row * DD);
  int i = threadIdx.x;            // 128 threads * float4 = 512
  float4 a = e[i], b = p[i];
  float4 r;
  r.x = a.x + b.x; r.y = a.y + b.y; r.z = a.z + b.z; r.w = a.w + b.w;
  o[i] = r;
}

// ---------------- layernorm (one wave per row of 512) ----------------
template <int WF32>
__global__ __launch_bounds__(256) void ln_kernel(const float* __restrict__ h, const float* __restrict__ w,
                                                 const float* __restrict__ b, float* __restrict__ uf,
                                                 unsigned short* __restrict__ ub) {
  int row = blockIdx.x * 4 + (threadIdx.x >> 6);
  int lane = threadIdx.x & 63;
  const float* hr = h + (long)row * DD + lane * 8;
  float x[8];
  *(float4*)(x) = *(const float4*)(hr);
  *(float4*)(x + 4) = *(const float4*)(hr + 4);
  float s = 0.f;
#pragma unroll
  for (int i = 0; i < 8; ++i) s += x[i];
#pragma unroll
  for (int off = 32; off; off >>= 1) s += __shfl_xor(s, off);
  float mu = s * (1.f / 512.f);
  float q = 0.f;
#pragma unroll
  for (int i = 0; i < 8; ++i) { x[i] -= mu; q += x[i] * x[i]; }
#pragma unroll
  for (int off = 32; off; off >>= 1) q += __shfl_xor(q, off);
  float rstd = rsqrtf(q * (1.f / 512.f) + 1e-5f);
  float wv[8], bv[8];
  *(float4*)(wv) = *(const float4*)(w + lane * 8);
  *(float4*)(wv + 4) = *(const float4*)(w + lane * 8 + 4);
  *(float4*)(bv) = *(const float4*)(b + lane * 8);
  *(float4*)(bv + 4) = *(const float4*)(b + lane * 8 + 4);
  float y[8];
  s16x8 pk;
#pragma unroll
  for (int i = 0; i < 8; ++i) {
    y[i] = x[i] * rstd * wv[i] + bv[i];
    pk[i] = (short)f2bf(y[i]);
  }
  if (WF32) {
    float* up = uf + (long)row * DD + lane * 8;
    *(float4*)(up) = *(const float4*)(y);
    *(float4*)(up + 4) = *(const float4*)(y + 4);
  }
  *(s16x8*)(ub + (long)row * DD + lane * 8) = pk;
}

// ---------------- SSM scan (chunked, exact) ----------------
// h[t] = lam*h[t-1] + Bu[t]; 64 chunks of 32 steps.
__global__ void scan1_kernel(const float* __restrict__ Bu, const float* __restrict__ ll,
                             float* __restrict__ E) {
  int s = threadIdx.x;
  int c = blockIdx.x & 63;
  int b = blockIdx.x >> 6;
  float lam = 1.f / (1.f + __expf(-ll[s]));
  const float* p = Bu + ((long)b * TT + c * 32) * SS + s;
  float hacc = 0.f;
#pragma unroll
  for (int i = 0; i < 32; ++i) hacc = fmaf(lam, hacc, p[i * SS]);
  E[((long)b * 64 + c) * SS + s] = hacc;
}

__global__ void scan2_kernel(const float* __restrict__ E, const float* __restrict__ ll,
                             float* __restrict__ Hin) {
  int tid = threadIdx.x;  // 0..511
  int s = tid & 255;
  int b = tid >> 8;
  float lam = 1.f / (1.f + __expf(-ll[s]));
  float l2 = lam * lam, l4 = l2 * l2, l8 = l4 * l4, l16 = l8 * l8, l32 = l16 * l16;
  float carry = 0.f;
  for (int c = 0; c < 64; ++c) {
    long idx = ((long)b * 64 + c) * SS + s;
    Hin[idx] = carry;
    carry = fmaf(l32, carry, E[idx]);
  }
}

__global__ void scan3_kernel(const float* __restrict__ Bu, const float* __restrict__ ll,
                             const float* __restrict__ Hin, unsigned short* __restrict__ hst) {
  int s = threadIdx.x;
  int c = blockIdx.x & 63;
  int b = blockIdx.x >> 6;
  float lam = 1.f / (1.f + __expf(-ll[s]));
  const float* p = Bu + ((long)b * TT + c * 32) * SS + s;
  unsigned short* o = hst + ((long)b * TT + c * 32) * SS + s;
  float hacc = Hin[((long)b * 64 + c) * SS + s];
#pragma unroll
  for (int i = 0; i < 32; ++i) {
    hacc = fmaf(lam, hacc, p[i * SS]);
    o[i * SS] = f2bf(hacc);
  }
}

// ---------------- bf16 MFMA GEMM: out[m,n] = sum_k A[m,k] * W[n,k] ----------------
// 128x128 tile, BK=32, 256 threads (4 waves, each 64x64 via 4x4 frags of 16x16x32).
// EPI: 0 store f32; 1 h += acc + Dp[n]*u[m,n]; 2 store bf16 silu(acc);
//      3 store bf16 e2[idx]*acc; 4 of += acc; 5 store f32 acc + e0[n]
template <int EPI>
__global__ __launch_bounds__(256) void gemm_bt(const unsigned short* __restrict__ A,
                                               const unsigned short* __restrict__ W, int mtiles, int N,
                                               int K, float* __restrict__ of,
                                               unsigned short* __restrict__ ob,
                                               const float* __restrict__ e0,
                                               const float* __restrict__ e1,
                                               const unsigned short* __restrict__ e2) {
  __shared__ unsigned short As[128 * 32];
  __shared__ unsigned short Ws[128 * 32];
  int bm = blockIdx.x % mtiles;
  int bn = blockIdx.x / mtiles;
  int t = threadIdx.x, lane = t & 63, wv = t >> 6;
  int wm = (wv >> 1) * 64, wn = (wv & 1) * 64;
  f32x4 acc[4][4] = {};
  const unsigned short* Ab = A + (long)bm * 128 * K;
  const unsigned short* Wb = W + (long)bn * 128 * K;
  int r0 = t >> 2;            // rows 0..63
  int eo = (t & 3) * 8;       // 8-elem (16B) sub-offset within 64B row-chunk
  int r16 = lane & 15, kg = (lane >> 4) * 8;

  for (int kt = 0; kt < K; kt += 32) {
    s16x8 a0 = *(const s16x8*)(Ab + (long)r0 * K + kt + eo);
    s16x8 a1 = *(const s16x8*)(Ab + (long)(r0 + 64) * K + kt + eo);
    s16x8 w0 = *(const s16x8*)(Wb + (long)r0 * K + kt + eo);
    s16x8 w1 = *(const s16x8*)(Wb + (long)(r0 + 64) * K + kt + eo);
    __syncthreads();
    *(s16x8*)(As + t * 8) = a0;
    *(s16x8*)(As + t * 8 + 2048) = a1;
    *(s16x8*)(Ws + t * 8) = w0;
    *(s16x8*)(Ws + t * 8 + 2048) = w1;
    __syncthreads();
    s16x8 af[4], wf[4];
#pragma unroll
    for (int f = 0; f < 4; ++f) af[f] = *(const s16x8*)(As + (wm + f * 16 + r16) * 32 + kg);
#pragma unroll
    for (int f = 0; f < 4; ++f) wf[f] = *(const s16x8*)(Ws + (wn + f * 16 + r16) * 32 + kg);
#pragma unroll
    for (int fm = 0; fm < 4; ++fm)
#pragma unroll
      for (int fn = 0; fn < 4; ++fn)
        acc[fm][fn] = __builtin_amdgcn_mfma_f32_16x16x32_bf16(af[fm], wf[fn], acc[fm][fn], 0, 0, 0);
  }

  long mb = (long)bm * 128 + wm + ((lane >> 4) * 4);
  int nb = bn * 128 + wn + (lane & 15);
#pragma unroll
  for (int fm = 0; fm < 4; ++fm) {
#pragma unroll
    for (int j = 0; j < 4; ++j) {
      long m = mb + fm * 16 + j;
#pragma unroll
      for (int fn = 0; fn < 4; ++fn) {
        int n = nb + fn * 16;
        long idx = m * N + n;
        float v = acc[fm][fn][j];
        if constexpr (EPI == 0) {
          of[idx] = v;
        } else if constexpr (EPI == 1) {
          of[idx] += v + e0[n] * e1[idx];
        } else if constexpr (EPI == 2) {
          float sg = v / (1.f + __expf(-v));
          ob[idx] = f2bf(sg);
        } else if constexpr (EPI == 3) {
          ob[idx] = f2bf(bf2f(e2[idx]) * v);
        } else if constexpr (EPI == 4) {
          of[idx] += v;
        } else {
          of[idx] = v + e0[n];
        }
      }
    }
  }
}

// ---------------- launch ----------------
extern "C" void kernel_launch(void* const* d_in, const int* in_sizes, int n_in, void* d_out,
                              int out_size, void* d_ws, size_t ws_size, hipStream_t stream) {
  const int* x = (const int*)d_in[0];
  const float* emb = (const float*)d_in[1];
  const float* pos = (const float*)d_in[2];
  const float* loglam = (const float*)d_in[3];
  const float* Bw = (const float*)d_in[4];
  const float* Cw = (const float*)d_in[5];
  const float* Dp = (const float*)d_in[6];
  const float* n1w = (const float*)d_in[7];
  const float* n1b = (const float*)d_in[8];
  const float* n2w = (const float*)d_in[9];
  const float* n2b = (const float*)d_in[10];
  const float* w1 = (const float*)d_in[11];
  const float* w2 = (const float*)d_in[12];
  const float* w3 = (const float*)d_in[13];
  const float* now_ = (const float*)d_in[14];
  const float* nob = (const float*)d_in[15];
  const float* headW = (const float*)d_in[16];
  const float* headb = (const float*)d_in[17];

  // persistent-through-head buffers in ws (~37MB)
  unsigned short* headW_bf = (unsigned short*)d_ws;
  unsigned short* hf_bf = (unsigned short*)((char*)d_ws + (size_t)VV * DD * 2);

  // layer-time scratch lives in d_out (dead before head GEMM writes it)
  char* ob_ = (char*)d_out;
  float* h = (float*)(ob_ + 0);                          // 8.39MB
  float* u = (float*)(ob_ + 8388608);                    // 8.39MB
  unsigned short* ubf = (unsigned short*)(ob_ + 16777216);  // 4.19MB (ln1 & ln2 out)
  float* Bu = (float*)(ob_ + 20971520);                  // 4.19MB
  unsigned short* hst = (unsigned short*)(ob_ + 25165824);  // 2.10MB
  float* E = (float*)(ob_ + 27262976);                   // 131KB
  float* Hin = (float*)(ob_ + 27394048);                 // 131KB
  unsigned short* s1 = (unsigned short*)(ob_ + 27525120);   // 11.53MB
  unsigned short* gate = (unsigned short*)(ob_ + 39059456); // 11.53MB
  unsigned short* Bw_bf = (unsigned short*)(ob_ + 50593792);
  unsigned short* Cw_bf = (unsigned short*)(ob_ + 51642368);
  unsigned short* w1_bf = (unsigned short*)(ob_ + 52690944);
  unsigned short* w2_bf = (unsigned short*)(ob_ + 58458112);
  unsigned short* w3_bf = (unsigned short*)(ob_ + 64225280);

  cast_kernel<<<2048, 256, 0, stream>>>(Bw, Bw_bf, (long)LL * SS * DD);
  cast_kernel<<<2048, 256, 0, stream>>>(Cw, Cw_bf, (long)LL * DD * SS);
  cast_kernel<<<64000, 256, 0, stream>>>(headW, headW_bf, (long)VV * DD);
  cast_pad_rows_kernel<<<11264, 256, 0, stream>>>(w1, w1_bf, DFF_, DFFP, DD);
  cast_pad_rows_kernel<<<11264, 256, 0, stream>>>(w2, w2_bf, DFF_, DFFP, DD);
  cast_pad_cols_kernel<<<11264, 256, 0, stream>>>(w3, w3_bf, DD, DFF_, DFFP);
  embed_kernel<<<BT, 128, 0, stream>>>(x, emb, pos, h);

  for (int l = 0; l < LL; ++l) {
    ln_kernel<1><<<BT / 4, 256, 0, stream>>>(h, n1w + l * DD, n1b + l * DD, u, ubf);
    gemm_bt<0><<<32 * (SS / 128), 256, 0, stream>>>(ubf, Bw_bf + (long)l * SS * DD, 32, SS, DD, Bu,
                                                    nullptr, nullptr, nullptr, nullptr);
    scan1_kernel<<<128, 256, 0, stream>>>(Bu, loglam + l * SS, E);
    scan2_kernel<<<1, 512, 0, stream>>>(E, loglam + l * SS, Hin);
    scan3_kernel<<<128, 256, 0, stream>>>(Bu, loglam + l * SS, Hin, hst);
    gemm_bt<1><<<32 * (DD / 128), 256, 0, stream>>>(hst, Cw_bf + (long)l * DD * SS, 32, DD, SS, h,
                                                    nullptr, Dp + l * DD, u, nullptr);
    ln_kernel<0><<<BT / 4, 256, 0, stream>>>(h, n2w + l * DD, n2b + l * DD, nullptr, ubf);
    gemm_bt<2><<<32 * (DFFP / 128), 256, 0, stream>>>(ubf, w1_bf + (long)l * DFFP * DD, 32, DFFP, DD,
                                                      nullptr, s1, nullptr, nullptr, nullptr);
    gemm_bt<3><<<32 * (DFFP / 128), 256, 0, stream>>>(ubf, w2_bf + (long)l * DFFP * DD, 32, DFFP, DD,
                                                      nullptr, gate, nullptr, nullptr, s1);
    gemm_bt<4><<<32 * (DD / 128), 256, 0, stream>>>(gate, w3_bf + (long)l * DD * DFFP, 32, DD, DFFP, h,
                                                    nullptr, nullptr, nullptr, nullptr);
  }
  ln_kernel<0><<<BT / 4, 256, 0, stream>>>(h, now_, nob, nullptr, hf_bf);
  gemm_bt<5><<<32 * (VV / 128), 256, 0, stream>>>(hf_bf, headW_bf, 32, VV, DD, (float*)d_out, nullptr,
                                                  headb, nullptr, nullptr);
}

// Round 2
// 1248.599 us; speedup vs baseline: 1.0598x; 1.0598x over previous
//
#include <hip/hip_runtime.h>
#include <hip/hip_bf16.h>

#define TT 2048
#define BT 4096
#define DD 512
#define SS 256
#define VV 32000
#define LL 4
#define DFF_ 1368
#define DFFP 1408

typedef __attribute__((ext_vector_type(8))) short s16x8;
typedef __attribute__((ext_vector_type(4))) float f32x4;

static __device__ __forceinline__ unsigned short f2bf(float x) {
  __hip_bfloat16 t = __float2bfloat16(x);
  return __builtin_bit_cast(unsigned short, t);
}
static __device__ __forceinline__ float bf2f(unsigned short u) {
  __hip_bfloat16 t = __builtin_bit_cast(__hip_bfloat16, u);
  return __bfloat162float(t);
}

// async global->LDS, 16B per lane. LDS dest: wave-uniform base + lane*16,
// which matches our linear As[t*8] layout exactly.
static __device__ __forceinline__ void gl2lds16(const unsigned short* g, unsigned short* l) {
  __builtin_amdgcn_global_load_lds(
      (const __attribute__((address_space(1))) unsigned int*)(g),
      (__attribute__((address_space(3))) unsigned int*)(l), 16, 0, 0);
}

// ---------------- cast kernels (8-wide vectorized) ----------------
__global__ void cast8_kernel(const float* __restrict__ s, unsigned short* __restrict__ d, long n8) {
  long i = (long)blockIdx.x * 256 + threadIdx.x;
  if (i >= n8) return;
  const float* p = s + i * 8;
  float4 a = *(const float4*)p, b = *(const float4*)(p + 4);
  s16x8 o;
  o[0] = (short)f2bf(a.x); o[1] = (short)f2bf(a.y); o[2] = (short)f2bf(a.z); o[3] = (short)f2bf(a.w);
  o[4] = (short)f2bf(b.x); o[5] = (short)f2bf(b.y); o[6] = (short)f2bf(b.z); o[7] = (short)f2bf(b.w);
  *(s16x8*)(d + i * 8) = o;
}

// w1,w2 [LL][DFF_][DD] -> comb [LL][2*DFFP][DD]; row 2f = w1_f, 2f+1 = w2_f, f>=DFF_ zero
__global__ void cast_ilv8_kernel(const float* __restrict__ w1, const float* __restrict__ w2,
                                 unsigned short* __restrict__ d) {
  long i = (long)blockIdx.x * 256 + threadIdx.x;
  if (i >= (long)LL * 2 * DFFP * 64) return;
  int c8 = (int)(i & 63);
  long t2 = i >> 6;
  int r = (int)(t2 % (2 * DFFP));
  int l = (int)(t2 / (2 * DFFP));
  int f = r >> 1;
  s16x8 o = {0, 0, 0, 0, 0, 0, 0, 0};
  if (f < DFF_) {
    const float* src = ((r & 1) ? w2 : w1) + ((long)l * DFF_ + f) * DD + c8 * 8;
    float4 a = *(const float4*)src, b = *(const float4*)(src + 4);
    o[0] = (short)f2bf(a.x); o[1] = (short)f2bf(a.y); o[2] = (short)f2bf(a.z); o[3] = (short)f2bf(a.w);
    o[4] = (short)f2bf(b.x); o[5] = (short)f2bf(b.y); o[6] = (short)f2bf(b.z); o[7] = (short)f2bf(b.w);
  }
  *(s16x8*)(d + ((long)l * (2 * DFFP) + r) * DD + c8 * 8) = o;
}

// w3 [LL][DD][DFF_] -> [LL][DD][DFFP], cols >= DFF_ zero (DFF_ = 171*8, multiple of 8)
__global__ void cast_padc8_kernel(const float* __restrict__ s, unsigned short* __restrict__ d) {
  long i = (long)blockIdx.x * 256 + threadIdx.x;
  if (i >= (long)LL * DD * (DFFP / 8)) return;
  int g = (int)(i % (DFFP / 8));
  long row = i / (DFFP / 8);  // 0 .. LL*DD-1
  s16x8 o = {0, 0, 0, 0, 0, 0, 0, 0};
  if (g < DFF_ / 8) {
    const float* src = s + row * DFF_ + g * 8;
    float4 a = *(const float4*)src, b = *(const float4*)(src + 4);
    o[0] = (short)f2bf(a.x); o[1] = (short)f2bf(a.y); o[2] = (short)f2bf(a.z); o[3] = (short)f2bf(a.w);
    o[4] = (short)f2bf(b.x); o[5] = (short)f2bf(b.y); o[6] = (short)f2bf(b.z); o[7] = (short)f2bf(b.w);
  }
  *(s16x8*)(d + row * DFFP + g * 8) = o;
}

// ---------------- embedding ----------------
__global__ void embed_kernel(const int* __restrict__ x, const float* __restrict__ emb,
                             const float* __restrict__ pos, float* __restrict__ h) {
  int row = blockIdx.x;
  int t = row & (TT - 1);
  int tok = x[row];
  const float4* e = (const float4*)(emb + (long)tok * DD);
  const float4* p = (const float4*)(pos + (long)t * DD);
  float4* o = (float4*)(h + (long)row * DD);
  int i = threadIdx.x;
  float4 a = e[i], b = p[i];
  float4 r;
  r.x = a.x + b.x; r.y = a.y + b.y; r.z = a.z + b.z; r.w = a.w + b.w;
  o[i] = r;
}

// ---------------- layernorm (one wave per row of 512) ----------------
template <int WF32>
__global__ __launch_bounds__(256) void ln_kernel(const float* __restrict__ h, const float* __restrict__ w,
                                                 const float* __restrict__ b, float* __restrict__ uf,
                                                 unsigned short* __restrict__ ub) {
  int row = blockIdx.x * 4 + (threadIdx.x >> 6);
  int lane = threadIdx.x & 63;
  const float* hr = h + (long)row * DD + lane * 8;
  float x[8];
  *(float4*)(x) = *(const float4*)(hr);
  *(float4*)(x + 4) = *(const float4*)(hr + 4);
  float s = 0.f;
#pragma unroll
  for (int i = 0; i < 8; ++i) s += x[i];
#pragma unroll
  for (int off = 32; off; off >>= 1) s += __shfl_xor(s, off);
  float mu = s * (1.f / 512.f);
  float q = 0.f;
#pragma unroll
  for (int i = 0; i < 8; ++i) { x[i] -= mu; q += x[i] * x[i]; }
#pragma unroll
  for (int off = 32; off; off >>= 1) q += __shfl_xor(q, off);
  float rstd = rsqrtf(q * (1.f / 512.f) + 1e-5f);
  float wv[8], bv[8];
  *(float4*)(wv) = *(const float4*)(w + lane * 8);
  *(float4*)(wv + 4) = *(const float4*)(w + lane * 8 + 4);
  *(float4*)(bv) = *(const float4*)(b + lane * 8);
  *(float4*)(bv + 4) = *(const float4*)(b + lane * 8 + 4);
  float y[8];
  s16x8 pk;
#pragma unroll
  for (int i = 0; i < 8; ++i) {
    y[i] = x[i] * rstd * wv[i] + bv[i];
    pk[i] = (short)f2bf(y[i]);
  }
  if (WF32) {
    float* up = uf + (long)row * DD + lane * 8;
    *(float4*)(up) = *(const float4*)(y);
    *(float4*)(up + 4) = *(const float4*)(y + 4);
  }
  *(s16x8*)(ub + (long)row * DD + lane * 8) = pk;
}

// ---------------- SSM scan (chunked, exact) ----------------
__global__ void scan1_kernel(const float* __restrict__ Bu, const float* __restrict__ ll,
                             float* __restrict__ E) {
  int s = threadIdx.x;
  int c = blockIdx.x & 63;
  int b = blockIdx.x >> 6;
  float lam = 1.f / (1.f + __expf(-ll[s]));
  const float* p = Bu + ((long)b * TT + c * 32) * SS + s;
  float hacc = 0.f;
#pragma unroll
  for (int i = 0; i < 32; ++i) hacc = fmaf(lam, hacc, p[i * SS]);
  E[((long)b * 64 + c) * SS + s] = hacc;
}

// register-buffered: one mem round trip instead of 64 dependent ones
__global__ void scan2_kernel(const float* __restrict__ E, const float* __restrict__ ll,
                             float* __restrict__ Hin) {
  int tid = threadIdx.x;
  int s = tid & 255;
  int b = tid >> 8;
  float lam = 1.f / (1.f + __expf(-ll[s]));
  float l2 = lam * lam, l4 = l2 * l2, l8 = l4 * l4, l16 = l8 * l8, l32 = l16 * l16;
  const float* Ep = E + (long)b * 64 * SS + s;
  float* Hp = Hin + (long)b * 64 * SS + s;
  float e[64];
#pragma unroll
  for (int c = 0; c < 64; ++c) e[c] = Ep[c * SS];
  float carry = 0.f;
#pragma unroll
  for (int c = 0; c < 64; ++c) {
    float t = e[c];
    e[c] = carry;
    carry = fmaf(l32, carry, t);
  }
#pragma unroll
  for (int c = 0; c < 64; ++c) Hp[c * SS] = e[c];
}

__global__ void scan3_kernel(const float* __restrict__ Bu, const float* __restrict__ ll,
                             const float* __restrict__ Hin, unsigned short* __restrict__ hst) {
  int s = threadIdx.x;
  int c = blockIdx.x & 63;
  int b = blockIdx.x >> 6;
  float lam = 1.f / (1.f + __expf(-ll[s]));
  const float* p = Bu + ((long)b * TT + c * 32) * SS + s;
  unsigned short* o = hst + ((long)b * TT + c * 32) * SS + s;
  float hacc = Hin[((long)b * 64 + c) * SS + s];
#pragma unroll
  for (int i = 0; i < 32; ++i) {
    hacc = fmaf(lam, hacc, p[i * SS]);
    o[i * SS] = f2bf(hacc);
  }
}

// ---------------- bf16 MFMA GEMM: out[m,n] = sum_k A[m,k] * W[n,k] ----------------
// 128x128 tile, BK=32, 256 threads (4 waves, 64x64 each, 4x4 frags of 16x16x32).
// Staging via global_load_lds width=16 (m97 structure).
// EPI: 0 store f32; 1 h += acc + Dp[n]*u[m,n]; 4 of += acc; 5 store f32 acc + e0[n];
//      6 fused swiglu gate: cols pair (even=w1,odd=w2), store bf16 silu(x1)*x2 at n/2
template <int EPI>
__global__ __launch_bounds__(256) void gemm_bt(const unsigned short* __restrict__ A,
                                               const unsigned short* __restrict__ W, int mtiles, int N,
                                               int K, float* __restrict__ of,
                                               unsigned short* __restrict__ ob,
                                               const float* __restrict__ e0,
                                               const float* __restrict__ e1) {
  __shared__ unsigned short As[128 * 32];
  __shared__ unsigned short Ws[128 * 32];
  int bm = blockIdx.x % mtiles;
  int bn = blockIdx.x / mtiles;
  int t = threadIdx.x, lane = t & 63;
  int wv = t >> 6;
  int wm = (wv >> 1) * 64, wn = (wv & 1) * 64;
  f32x4 acc[4][4] = {};
  const unsigned short* Ab = A + (long)bm * 128 * K;
  const unsigned short* Wb = W + (long)bn * 128 * K;
  int r0 = t >> 2;       // rows 0..63
  int eo = (t & 3) * 8;  // 16B sub-offset within row's 64B chunk
  int r16 = lane & 15, kg = (lane >> 4) * 8;

  for (int kt = 0; kt < K; kt += 32) {
    __syncthreads();  // prev iteration's ds_reads done before overwrite
    gl2lds16(Ab + (long)r0 * K + kt + eo, As + t * 8);
    gl2lds16(Ab + (long)(r0 + 64) * K + kt + eo, As + 2048 + t * 8);
    gl2lds16(Wb + (long)r0 * K + kt + eo, Ws + t * 8);
    gl2lds16(Wb + (long)(r0 + 64) * K + kt + eo, Ws + 2048 + t * 8);
    __syncthreads();  // compiler drains vmcnt(0) before barrier -> data landed
    s16x8 af[4], wf[4];
#pragma unroll
    for (int f = 0; f < 4; ++f) af[f] = *(const s16x8*)(As + (wm + f * 16 + r16) * 32 + kg);
#pragma unroll
    for (int f = 0; f < 4; ++f) wf[f] = *(const s16x8*)(Ws + (wn + f * 16 + r16) * 32 + kg);
#pragma unroll
    for (int fm = 0; fm < 4; ++fm)
#pragma unroll
      for (int fn = 0; fn < 4; ++fn)
        acc[fm][fn] = __builtin_amdgcn_mfma_f32_16x16x32_bf16(af[fm], wf[fn], acc[fm][fn], 0, 0, 0);
  }

  long mb = (long)bm * 128 + wm + ((lane >> 4) * 4);
  int nb = bn * 128 + wn + (lane & 15);
#pragma unroll
  for (int fm = 0; fm < 4; ++fm) {
#pragma unroll
    for (int j = 0; j < 4; ++j) {
      long m = mb + fm * 16 + j;
#pragma unroll
      for (int fn = 0; fn < 4; ++fn) {
        int n = nb + fn * 16;
        long idx = m * N + n;
        float v = acc[fm][fn][j];
        if constexpr (EPI == 0) {
          of[idx] = v;
        } else if constexpr (EPI == 1) {
          of[idx] += v + e0[n] * e1[idx];
        } else if constexpr (EPI == 4) {
          of[idx] += v;
        } else if constexpr (EPI == 5) {
          of[idx] = v + e0[n];
        } else if constexpr (EPI == 6) {
          float po = __shfl_xor(v, 1);  // partner column (n^1): all lanes participate
          if ((lane & 1) == 0) {
            float sg = v / (1.f + __expf(-v));  // v = w1 col (even), po = w2 col (odd)
            ob[m * (long)(N >> 1) + (n >> 1)] = f2bf(sg * po);
          }
        }
      }
    }
  }
}

// ---------------- launch ----------------
extern "C" void kernel_launch(void* const* d_in, const int* in_sizes, int n_in, void* d_out,
                              int out_size, void* d_ws, size_t ws_size, hipStream_t stream) {
  const int* x = (const int*)d_in[0];
  const float* emb = (const float*)d_in[1];
  const float* pos = (const float*)d_in[2];
  const float* loglam = (const float*)d_in[3];
  const float* Bw = (const float*)d_in[4];
  const float* Cw = (const float*)d_in[5];
  const float* Dp = (const float*)d_in[6];
  const float* n1w = (const float*)d_in[7];
  const float* n1b = (const float*)d_in[8];
  const float* n2w = (const float*)d_in[9];
  const float* n2b = (const float*)d_in[10];
  const float* w1 = (const float*)d_in[11];
  const float* w2 = (const float*)d_in[12];
  const float* w3 = (const float*)d_in[13];
  const float* now_ = (const float*)d_in[14];
  const float* nob = (const float*)d_in[15];
  const float* headW = (const float*)d_in[16];
  const float* headb = (const float*)d_in[17];

  // persistent-through-head buffers in ws (~37MB)
  unsigned short* headW_bf = (unsigned short*)d_ws;
  unsigned short* hf_bf = (unsigned short*)((char*)d_ws + (size_t)VV * DD * 2);

  // layer-time scratch in d_out (dead before head GEMM writes it)
  char* ob_ = (char*)d_out;
  float* h = (float*)(ob_ + 0);                             // 8.39MB
  float* u = (float*)(ob_ + 8388608);                       // 8.39MB
  unsigned short* ubf = (unsigned short*)(ob_ + 16777216);  // 4.19MB
  float* Bu = (float*)(ob_ + 20971520);                     // 4.19MB
  unsigned short* hst = (unsigned short*)(ob_ + 25165824);  // 2.10MB
  float* E = (float*)(ob_ + 27262976);                      // 131KB
  float* Hin = (float*)(ob_ + 27394048);                    // 131KB
  unsigned short* gate = (unsigned short*)(ob_ + 27525120);   // 11.53MB
  unsigned short* Bw_bf = (unsigned short*)(ob_ + 39059456);  // 1.05MB
  unsigned short* Cw_bf = (unsigned short*)(ob_ + 40108032);  // 1.05MB
  unsigned short* w12_bf = (unsigned short*)(ob_ + 41156608); // 11.53MB (interleaved+padded)
  unsigned short* w3_bf = (unsigned short*)(ob_ + 52690944);  // 5.77MB -> ends 58.5MB < 524MB

  cast8_kernel<<<1024, 256, 0, stream>>>(Bw, Bw_bf, (long)LL * SS * DD / 8);
  cast8_kernel<<<1024, 256, 0, stream>>>(Cw, Cw_bf, (long)LL * DD * SS / 8);
  cast8_kernel<<<8000, 256, 0, stream>>>(headW, headW_bf, (long)VV * DD / 8);
  cast_ilv8_kernel<<<5632, 256, 0, stream>>>(w1, w2, w12_bf);
  cast_padc8_kernel<<<1408, 256, 0, stream>>>(w3, w3_bf);
  embed_kernel<<<BT, 128, 0, stream>>>(x, emb, pos, h);

  for (int l = 0; l < LL; ++l) {
    ln_kernel<1><<<BT / 4, 256, 0, stream>>>(h, n1w + l * DD, n1b + l * DD, u, ubf);
    gemm_bt<0><<<32 * (SS / 128), 256, 0, stream>>>(ubf, Bw_bf + (long)l * SS * DD, 32, SS, DD, Bu,
                                                    nullptr, nullptr, nullptr);
    scan1_kernel<<<128, 256, 0, stream>>>(Bu, loglam + l * SS, E);
    scan2_kernel<<<1, 512, 0, stream>>>(E, loglam + l * SS, Hin);
    scan3_kernel<<<128, 256, 0, stream>>>(Bu, loglam + l * SS, Hin, hst);
    gemm_bt<1><<<32 * (DD / 128), 256, 0, stream>>>(hst, Cw_bf + (long)l * DD * SS, 32, DD, SS, h,
                                                    nullptr, Dp + l * DD, u);
    ln_kernel<0><<<BT / 4, 256, 0, stream>>>(h, n2w + l * DD, n2b + l * DD, nullptr, ubf);
    gemm_bt<6><<<32 * (2 * DFFP / 128), 256, 0, stream>>>(ubf, w12_bf + (long)l * 2 * DFFP * DD, 32,
                                                          2 * DFFP, DD, nullptr, gate, nullptr,
                                                          nullptr);
    gemm_bt<4><<<32 * (DD / 128), 256, 0, stream>>>(gate, w3_bf + (long)l * DD * DFFP, 32, DD, DFFP,
                                                    h, nullptr, nullptr, nullptr);
  }
  ln_kernel<0><<<BT / 4, 256, 0, stream>>>(h, now_, nob, nullptr, hf_bf);
  gemm_bt<5><<<32 * (VV / 128), 256, 0, stream>>>(hf_bf, headW_bf, 32, VV, DD, (float*)d_out,
                                                  nullptr, headb, nullptr);
}